// Round 20
// baseline (204.932 us; speedup 1.0000x reference)
//
#include <hip/hip_runtime.h>
#include <hip/hip_bf16.h>
#include <math.h>

#define BB 32
#define NN 4096
#define DD 512
#define HH 128
#define NCH 128          // 32-row chunks per batch
#define LN_EPS 1e-5f
#define MEPS 1e-8f

typedef __attribute__((ext_vector_type(8))) short bf16x8;
typedef __attribute__((ext_vector_type(4))) float f32x4;

__device__ __forceinline__ unsigned pk_bf16(float a, float b) {
    unsigned ua = __float_as_uint(a); ua = (ua + 0x7FFFu + ((ua >> 16) & 1u)) >> 16;
    unsigned ub = __float_as_uint(b); ub = (ub + 0x7FFFu + ((ub >> 16) & 1u)) >> 16;
    return ua | (ub << 16);
}
__device__ __forceinline__ unsigned short bf16_1(float a) {
    unsigned ua = __float_as_uint(a);
    return (unsigned short)((ua + 0x7FFFu + ((ua >> 16) & 1u)) >> 16);
}

// ---- prep: mask sniff+expand (blocks 0..511) ------------------------------
// ---- + W1 -> bf16 in MFMA-FRAGMENT-MAJOR order (blocks 512..767) ----------
__global__ __launch_bounds__(256) void gmsp_prep(
    const void* __restrict__ mask, unsigned char* __restrict__ m8,
    const float* __restrict__ w1, unsigned short* __restrict__ w1f)
{
    int blk = blockIdx.x, t = threadIdx.x;
    if (blk < 512) {
        __shared__ int sf[2];
        const unsigned* mu = (const unsigned*)mask;
        bool f32f = false, i8f = false;
#pragma unroll
        for (int i = 0; i < 4; ++i) {
            unsigned v = mu[t + i * 256];
            f32f |= (v == 0x3F800000u);
            i8f  |= (v > 1u) && (v != 0x3F800000u);
        }
        if (t == 0) { sf[0] = 0; sf[1] = 0; }
        __syncthreads();
        int wf32 = __any((int)f32f), wi8 = __any((int)i8f);
        if ((t & 63) == 0) {
            if (wf32) atomicOr(&sf[0], 1);
            if (wi8)  atomicOr(&sf[1], 1);
        }
        __syncthreads();
        int fmt = sf[0] ? 2 : (sf[1] ? 1 : 0);
        int i = blk * 256 + t;
        unsigned char v;
        if (fmt == 1)      v = ((const unsigned char*)mask)[i] != 0;
        else if (fmt == 2) v = ((const float*)mask)[i] != 0.0f;
        else               v = ((const int*)mask)[i] != 0;
        m8[i] = v;
    } else {
        int idx = (blk - 512) * 256 + t;   // 65536 bf16 elements of w1f
        int j = idx & 7;
        int e = idx >> 3;
        int lane = e & 63;
        int half = (e >> 6) & 1;
        int s = (e >> 7) & 15;
        int g2 = (e >> 11) & 3;
        int h = g2 * 32 + half * 16 + (lane & 15);
        int k = s * 32 + (lane >> 4) * 8 + j;
        w1f[(size_t)e * 8 + j] = bf16_1(w1[(size_t)k * HH + h]);
    }
}

// ---- fused: K-split 16KB LDS -> 8 blocks/CU; replay+pools from global x ----
__global__ __launch_bounds__(256, 8) void gmsp_fused(
    const float* __restrict__ x, const unsigned short* __restrict__ w1f,
    const float* __restrict__ b1, const float* __restrict__ w2,
    const float* __restrict__ b2, const unsigned char* __restrict__ m8,
    float* __restrict__ attnp, float* __restrict__ sump, float* __restrict__ maxp,
    float* __restrict__ mc, float* __restrict__ sc, float* __restrict__ cnt)
{
    __shared__ char At[16 * 1024];                    // 32 rows x 256 cols bf16 (one K-half)
    __shared__ float sred[32][4] __attribute__((aligned(16)));

    const int t = threadIdx.x;
    const int lane = t & 63, wid = t >> 6;
    const int l15 = lane & 15, lq = (lane >> 4) & 3;
    const int blk = blockIdx.x;
    const int b = blk >> 7, ch = blk & 127;
    const size_t row0 = (size_t)b * NN + (size_t)ch * 32;

    const char* wf = (const char*)w1f + (size_t)wid * 32768 + (size_t)lane * 16;
    const int swz = (l15 & 7) << 4;
    const char* ar0 = At + l15 * 512;
    const char* ar1 = At + (16 + l15) * 512;

    f32x4 acc00 = (f32x4)0.f, acc01 = (f32x4)0.f, acc10 = (f32x4)0.f, acc11 = (f32x4)0.f;

#pragma unroll
    for (int h = 0; h < 2; ++h) {
        // ---- stage+convert K-half h: 8 float4 loads/thread -> bf16 At ----
#pragma unroll
        for (int j = 0; j < 8; ++j) {
            const int idx = j * 256 + t;
            const int row = idx >> 6;                 // 0..31 (64 thr/row)
            const int c64 = idx & 63;                 // 8B granule within 512B row
            float4 v = *(const float4*)(x + (row0 + row) * DD + h * 256 + c64 * 4);
            uint2 pw; pw.x = pk_bf16(v.x, v.y); pw.y = pk_bf16(v.z, v.w);
            *(uint2*)(At + row * 512 + ((c64 * 8) ^ ((row & 7) << 4))) = pw;
        }
        __syncthreads();                              // At[h] ready

        // ---- MFMA K-half h: 8 steps, accs carry across halves ----
#pragma unroll
        for (int sp = 0; sp < 8; ++sp) {
            const int s = h * 8 + sp;
            bf16x8 bf0 = *(const bf16x8*)(wf + s * 2048);          // coalesced 1KB
            bf16x8 bf1 = *(const bf16x8*)(wf + s * 2048 + 1024);
            const int co = (sp * 64 + lq * 16) ^ swz;
            bf16x8 a0 = *(const bf16x8*)(ar0 + co);
            bf16x8 a1 = *(const bf16x8*)(ar1 + co);
            acc00 = __builtin_amdgcn_mfma_f32_16x16x32_bf16(a0, bf0, acc00, 0, 0, 0);
            acc01 = __builtin_amdgcn_mfma_f32_16x16x32_bf16(a0, bf1, acc01, 0, 0, 0);
            acc10 = __builtin_amdgcn_mfma_f32_16x16x32_bf16(a1, bf0, acc10, 0, 0, 0);
            acc11 = __builtin_amdgcn_mfma_f32_16x16x32_bf16(a1, bf1, acc11, 0, 0, 0);
        }
        __syncthreads();                              // At reads done (h=0: before overwrite)
    }

    // ---- tanh + w2-dot; reduce across the 16 h-lanes ----
    {
        const float b10 = b1[wid * 32 + l15], b11 = b1[wid * 32 + 16 + l15];
        const float w20 = w2[wid * 32 + l15], w21 = w2[wid * 32 + 16 + l15];
#pragma unroll
        for (int rf = 0; rf < 2; ++rf) {
            f32x4 aA = rf ? acc10 : acc00;
            f32x4 aB = rf ? acc11 : acc01;
#pragma unroll
            for (int r = 0; r < 4; ++r) {
                float p0 = fminf(fmaxf(aA[r] + b10, -10.f), 10.f);
                float p1 = fminf(fmaxf(aB[r] + b11, -10.f), 10.f);
                float e0 = __expf(2.f * p0), e1 = __expf(2.f * p1);
                float v = (e0 - 1.f) / (e0 + 1.f) * w20 + (e1 - 1.f) / (e1 + 1.f) * w21;
                v += __shfl_xor(v, 1); v += __shfl_xor(v, 2);
                v += __shfl_xor(v, 4); v += __shfl_xor(v, 8);
                if (l15 == 0) sred[rf * 16 + lq * 4 + r][wid] = v;
            }
        }
    }
    __syncthreads();                                  // sred ready

    // ---- softmax, redundantly in every wave (identical results) ----
    float wv; unsigned mb;
    {
        const int rl = lane & 31;
        float4 s4 = *(const float4*)&sred[rl][0];
        float ssc = s4.x + s4.y + s4.z + s4.w + b2[0];
        bool val = m8[row0 + rl] != 0;
        mb = (unsigned)__ballot((int)val);            // bit r = row r valid (low 32)
        float score = val ? ssc : -INFINITY;
        float mx = score;
        mx = fmaxf(mx, __shfl_xor(mx, 1));  mx = fmaxf(mx, __shfl_xor(mx, 2));
        mx = fmaxf(mx, __shfl_xor(mx, 4));  mx = fmaxf(mx, __shfl_xor(mx, 8));
        mx = fmaxf(mx, __shfl_xor(mx, 16));
        wv = val ? __expf(score - mx) : 0.f;
        float ts = wv;
        ts += __shfl_xor(ts, 1); ts += __shfl_xor(ts, 2);
        ts += __shfl_xor(ts, 4); ts += __shfl_xor(ts, 8);
        ts += __shfl_xor(ts, 16);
        if (t == 0) {
            mc[blk] = mx; sc[blk] = ts;
            cnt[blk] = (float)__builtin_popcount(mb);
        }
    }

    // ---- replay + pools from global x (L2-hot), fully fp32 ----
    const float* xb = x + row0 * DD + 2 * t;
    float a0 = 0.f, a1 = 0.f, s0 = 0.f, s1 = 0.f;
    float m0 = -INFINITY, m1 = -INFINITY;
#pragma unroll 8
    for (int r = 0; r < 32; ++r) {
        float2 v = *(const float2*)(xb + (size_t)r * DD);
        float w = __shfl(wv, r);
        a0 = fmaf(w, v.x, a0); a1 = fmaf(w, v.y, a1);
        if (mb & (1u << r)) {                        // wave-uniform branch
            s0 += v.x; s1 += v.y;
            m0 = fmaxf(m0, v.x); m1 = fmaxf(m1, v.y);
        }
    }
    const size_t ob = (size_t)blk * DD + 2 * t;
    *(float2*)(attnp + ob) = make_float2(a0, a1);
    *(float2*)(sump + ob)  = make_float2(s0, s1);
    *(float2*)(maxp + ob)  = make_float2(m0, m1);
}

// ---- tail helpers (512-thread block reductions) ----------------------------
__device__ __forceinline__ float gmsp_bsum(float v, float* red, int t) {
    __syncthreads();
    red[t] = v; __syncthreads();
    for (int s = 256; s > 0; s >>= 1) { if (t < s) red[t] += red[t + s]; __syncthreads(); }
    return red[0];
}
__device__ __forceinline__ float gmsp_bmax(float v, float* red, int t) {
    __syncthreads();
    red[t] = v; __syncthreads();
    for (int s = 256; s > 0; s >>= 1) { if (t < s) red[t] = fmaxf(red[t], red[t + s]); __syncthreads(); }
    return red[0];
}

// ---- tail: 512 threads, one column/thread, k-split x4 MLP loops ------------
__global__ __launch_bounds__(512) void gmsp_tail(
    const float* __restrict__ attnp, const float* __restrict__ sump,
    const float* __restrict__ maxp, const float* __restrict__ mc,
    const float* __restrict__ sc, const float* __restrict__ cnt,
    const float* __restrict__ gate_w1, const float* __restrict__ gate_b1,
    const float* __restrict__ gln_g, const float* __restrict__ gln_b,
    const float* __restrict__ gate_w2, const float* __restrict__ gate_b2,
    const float* __restrict__ out_w, const float* __restrict__ out_b,
    const float* __restrict__ oln_g, const float* __restrict__ oln_b,
    float* __restrict__ out)
{
    __shared__ float comb[3 * DD];
    __shared__ float wvec[DD];
    __shared__ float red[512];
    __shared__ float ef[NCH];
    __shared__ float part[4][DD];
    int b = blockIdx.x, t = threadIdx.x;   // 512 threads; col = t

    float mcv = (t < NCH) ? mc[b * NCH + t] : -INFINITY;
    float M = gmsp_bmax(mcv, red, t);
    float e = (t < NCH && mcv != -INFINITY) ? __expf(mcv - M) : 0.f;
    if (t < NCH) ef[t] = e;
    float T = gmsp_bsum(e * ((t < NCH) ? sc[b * NCH + t] : 0.f), red, t);
    float C = gmsp_bsum((t < NCH) ? cnt[b * NCH + t] : 0.f, red, t);
    float invT = T > 0.f ? 1.f / T : 0.f;
    C = fmaxf(C, MEPS);
    __syncthreads();

    float ax = 0.f, sx = 0.f, mx = -INFINITY;
    for (int c = 0; c < NCH; ++c) {
        size_t base = (size_t)(b * NCH + c) * DD + t;
        ax = fmaf(ef[c], attnp[base], ax);
        sx += sump[base];
        mx = fmaxf(mx, maxp[base]);
    }
    ax *= invT;
    float meanx = sx / C;
    if (isinf(mx)) mx = 0.f;

    comb[t] = ax;
    comb[DD + t] = mx;
    comb[2 * DD + t] = meanx;
    __syncthreads();

    const int th = t & 127, kh = t >> 7;
    {
        float4 g4 = make_float4(0.f, 0.f, 0.f, 0.f);
        const float* gw = gate_w1 + (size_t)kh * 384 * DD + th * 4;
        for (int k = 0; k < 384; ++k) {
            float cv = comb[kh * 384 + k];
            float4 wv = *(const float4*)(gw + (size_t)k * DD);
            g4.x = fmaf(cv, wv.x, g4.x); g4.y = fmaf(cv, wv.y, g4.y);
            g4.z = fmaf(cv, wv.z, g4.z); g4.w = fmaf(cv, wv.w, g4.w);
        }
        *(float4*)&part[kh][th * 4] = g4;
    }
    __syncthreads();
    float gx = part[0][t] + part[1][t] + part[2][t] + part[3][t] + gate_b1[t];

    float mg = gmsp_bsum(gx, red, t) * (1.f / DD);
    float vg = gmsp_bsum(gx * gx, red, t) * (1.f / DD) - mg * mg;
    float inv = rsqrtf(vg + LN_EPS);
    gx = (gx - mg) * inv * gln_g[t] + gln_b[t];
    gx = 0.5f * gx * (1.f + erff(gx * 0.70710678118654752f));

    float l0 = gmsp_bsum(gx * gate_w2[t * 3 + 0], red, t) + gate_b2[0];
    float l1 = gmsp_bsum(gx * gate_w2[t * 3 + 1], red, t) + gate_b2[1];
    float l2 = gmsp_bsum(gx * gate_w2[t * 3 + 2], red, t) + gate_b2[2];
    float mxl = fmaxf(l0, fmaxf(l1, l2));
    float e0 = __expf(l0 - mxl), e1 = __expf(l1 - mxl), e2 = __expf(l2 - mxl);
    float ie = 1.f / (e0 + e1 + e2);
    float gw0 = e0 * ie, gw1 = e1 * ie, gw2 = e2 * ie;

    wvec[t] = ax * gw0 + mx * gw1 + meanx * gw2;
    __syncthreads();

    {
        float4 o4 = make_float4(0.f, 0.f, 0.f, 0.f);
        const float* ow = out_w + (size_t)kh * 128 * DD + th * 4;
        for (int k = 0; k < 128; ++k) {
            float wvk = wvec[kh * 128 + k];
            float4 w4 = *(const float4*)(ow + (size_t)k * DD);
            o4.x = fmaf(wvk, w4.x, o4.x); o4.y = fmaf(wvk, w4.y, o4.y);
            o4.z = fmaf(wvk, w4.z, o4.z); o4.w = fmaf(wvk, w4.w, o4.w);
        }
        *(float4*)&part[kh][th * 4] = o4;
    }
    __syncthreads();
    float ox = part[0][t] + part[1][t] + part[2][t] + part[3][t] + out_b[t];

    float mo = gmsp_bsum(ox, red, t) * (1.f / DD);
    float vo = gmsp_bsum(ox * ox, red, t) * (1.f / DD) - mo * mo;
    float io = rsqrtf(vo + LN_EPS);
    out[(size_t)b * DD + t] = (ox - mo) * io * oln_g[t] + oln_b[t];
}

extern "C" void kernel_launch(void* const* d_in, const int* in_sizes, int n_in,
                              void* d_out, int out_size, void* d_ws, size_t ws_size,
                              hipStream_t stream) {
    const float* x        = (const float*)d_in[0];
    const void*  mask     = d_in[1];
    const float* attn_w1  = (const float*)d_in[2];
    const float* attn_b1  = (const float*)d_in[3];
    const float* attn_w2  = (const float*)d_in[4];
    const float* attn_b2  = (const float*)d_in[5];
    const float* gate_w1  = (const float*)d_in[6];
    const float* gate_b1  = (const float*)d_in[7];
    const float* gln_g    = (const float*)d_in[8];
    const float* gln_b    = (const float*)d_in[9];
    const float* gate_w2  = (const float*)d_in[10];
    const float* gate_b2  = (const float*)d_in[11];
    const float* out_w    = (const float*)d_in[12];
    const float* out_b    = (const float*)d_in[13];
    const float* oln_g    = (const float*)d_in[14];
    const float* oln_b    = (const float*)d_in[15];
    float* out = (float*)d_out;

    char* p = (char*)d_ws;
    unsigned char* m8 = (unsigned char*)p;      p += (size_t)BB * NN;             // 128 KB
    unsigned short* w1f = (unsigned short*)p;   p += (size_t)DD * HH * 2;         // 128 KB
    float* attnp = (float*)p;                   p += (size_t)BB * NCH * DD * 4;   // 8 MB
    float* sump = (float*)p;                    p += (size_t)BB * NCH * DD * 4;   // 8 MB
    float* maxp = (float*)p;                    p += (size_t)BB * NCH * DD * 4;   // 8 MB
    float* mc = (float*)p;                      p += (size_t)BB * NCH * 4;
    float* sc = (float*)p;                      p += (size_t)BB * NCH * 4;
    float* cnt = (float*)p;                     p += (size_t)BB * NCH * 4;

    gmsp_prep<<<768, 256, 0, stream>>>(mask, m8, attn_w1, w1f);
    gmsp_fused<<<BB * NCH, 256, 0, stream>>>(x, w1f, attn_b1, attn_w2, attn_b2, m8,
                                             attnp, sump, maxp, mc, sc, cnt);
    gmsp_tail<<<BB, 512, 0, stream>>>(attnp, sump, maxp, mc, sc, cnt,
                                      gate_w1, gate_b1, gln_g, gln_b, gate_w2, gate_b2,
                                      out_w, out_b, oln_g, oln_b, out);
}

// Round 21
// 140.828 us; speedup vs baseline: 1.4552x; 1.4552x over previous
//
#include <hip/hip_runtime.h>
#include <hip/hip_bf16.h>
#include <math.h>

#define BB 32
#define NN 4096
#define DD 512
#define HH 128
#define NCH 128          // 32-row chunks per batch
#define LN_EPS 1e-5f
#define MEPS 1e-8f

typedef __attribute__((ext_vector_type(8))) short bf16x8;
typedef __attribute__((ext_vector_type(4))) float f32x4;

__device__ __forceinline__ unsigned pk_bf16(float a, float b) {
    unsigned ua = __float_as_uint(a); ua = (ua + 0x7FFFu + ((ua >> 16) & 1u)) >> 16;
    unsigned ub = __float_as_uint(b); ub = (ub + 0x7FFFu + ((ub >> 16) & 1u)) >> 16;
    return ua | (ub << 16);
}
__device__ __forceinline__ unsigned short bf16_1(float a) {
    unsigned ua = __float_as_uint(a);
    return (unsigned short)((ua + 0x7FFFu + ((ua >> 16) & 1u)) >> 16);
}
__device__ __forceinline__ float bflo(unsigned u) { return __uint_as_float(u << 16); }
__device__ __forceinline__ float bfhi(unsigned u) { return __uint_as_float(u & 0xFFFF0000u); }

// ---- prep: mask sniff+expand (blocks 0..511) ------------------------------
// ---- + W1 -> bf16 in MFMA-FRAGMENT-MAJOR order (blocks 512..767) ----------
__global__ __launch_bounds__(256) void gmsp_prep(
    const void* __restrict__ mask, unsigned char* __restrict__ m8,
    const float* __restrict__ w1, unsigned short* __restrict__ w1f)
{
    int blk = blockIdx.x, t = threadIdx.x;
    if (blk < 512) {
        __shared__ int sf[2];
        const unsigned* mu = (const unsigned*)mask;
        bool f32f = false, i8f = false;
#pragma unroll
        for (int i = 0; i < 4; ++i) {
            unsigned v = mu[t + i * 256];
            f32f |= (v == 0x3F800000u);
            i8f  |= (v > 1u) && (v != 0x3F800000u);
        }
        if (t == 0) { sf[0] = 0; sf[1] = 0; }
        __syncthreads();
        int wf32 = __any((int)f32f), wi8 = __any((int)i8f);
        if ((t & 63) == 0) {
            if (wf32) atomicOr(&sf[0], 1);
            if (wi8)  atomicOr(&sf[1], 1);
        }
        __syncthreads();
        int fmt = sf[0] ? 2 : (sf[1] ? 1 : 0);
        int i = blk * 256 + t;
        unsigned char v;
        if (fmt == 1)      v = ((const unsigned char*)mask)[i] != 0;
        else if (fmt == 2) v = ((const float*)mask)[i] != 0.0f;
        else               v = ((const int*)mask)[i] != 0;
        m8[i] = v;
    } else {
        int idx = (blk - 512) * 256 + t;   // 65536 bf16 elements of w1f
        int j = idx & 7;
        int e = idx >> 3;
        int lane = e & 63;
        int half = (e >> 6) & 1;
        int s = (e >> 7) & 15;
        int g2 = (e >> 11) & 3;
        int h = g2 * 32 + half * 16 + (lane & 15);
        int k = s * 32 + (lane >> 4) * 8 + j;
        w1f[(size_t)e * 8 + j] = bf16_1(w1[(size_t)k * HH + h]);
    }
}

// ---- fused: r11 verbatim (champion: ~122us, 4 blocks/CU) -------------------
__global__ __launch_bounds__(256, 4) void gmsp_fused(
    const float* __restrict__ x, const unsigned short* __restrict__ w1f,
    const float* __restrict__ b1, const float* __restrict__ w2,
    const float* __restrict__ b2, const unsigned char* __restrict__ m8,
    float* __restrict__ attnp, float* __restrict__ sump, float* __restrict__ maxp,
    float* __restrict__ mc, float* __restrict__ sc, float* __restrict__ cnt)
{
    __shared__ char At[32 * 1024];                    // 32 KB bf16 tile, XOR-swizzled
    __shared__ float sred[32][4] __attribute__((aligned(16)));
    __shared__ float wrow[32];
    __shared__ float cpool[2][512];

    const int t = threadIdx.x;
    const int lane = t & 63, wid = t >> 6;
    const int l15 = lane & 15, lq = (lane >> 4) & 3;
    const int blk = blockIdx.x;
    const int b = blk >> 7, ch = blk & 127;
    const size_t row0 = (size_t)b * NN + (size_t)ch * 32;

    // ---- stage: 16 coalesced float4 loads/thread ----
    float4 sreg[16];
    {
        const float4* xb = (const float4*)(x + row0 * DD);
#pragma unroll
        for (int j = 0; j < 16; ++j) sreg[j] = xb[j * 256 + t];
    }
    uint4 mq0 = *(const uint4*)(m8 + row0);
    uint4 mq1 = *(const uint4*)(m8 + row0 + 16);
    unsigned mwa[8] = {mq0.x, mq0.y, mq0.z, mq0.w, mq1.x, mq1.y, mq1.z, mq1.w};

    // ---- convert -> LDS bf16 (swizzled) + fp32 sum/max pool ----
    const int H = t >> 7;          // row parity
    const int c4 = t & 127;        // float4-column
    float ps[4] = {0.f, 0.f, 0.f, 0.f};
    float pm[4] = {-INFINITY, -INFINITY, -INFINITY, -INFINITY};
#pragma unroll
    for (int j = 0; j < 16; ++j) {
        const int row = 2 * j + H;
        float4 v = sreg[j];
        uint2 pw; pw.x = pk_bf16(v.x, v.y); pw.y = pk_bf16(v.z, v.w);
        *(uint2*)(At + row * 1024 + ((c4 * 8) ^ ((row & 7) << 4))) = pw;
        int mv = (mwa[j >> 1] >> ((2 * (j & 1) + H) * 8)) & 0xFF;
        if (mv) {   // wave-uniform (row uniform per wave)
            ps[0] += v.x; ps[1] += v.y; ps[2] += v.z; ps[3] += v.w;
            pm[0] = fmaxf(pm[0], v.x); pm[1] = fmaxf(pm[1], v.y);
            pm[2] = fmaxf(pm[2], v.z); pm[3] = fmaxf(pm[3], v.w);
        }
    }
    __syncthreads();

    // ---- MFMA: wave wid -> 32 rows x 32 h-cols [32*wid, 32*wid+32) ----
    const int hb = wid * 32;
    f32x4 acc00 = (f32x4)0.f, acc01 = (f32x4)0.f, acc10 = (f32x4)0.f, acc11 = (f32x4)0.f;
    {
        const char* wf = (const char*)w1f + (size_t)wid * 32768 + (size_t)lane * 16;
        const char* ar0 = At + l15 * 1024;
        const char* ar1 = At + (16 + l15) * 1024;
        const int swz = (l15 & 7) << 4;
#pragma unroll
        for (int s = 0; s < 16; ++s) {
            bf16x8 bf0 = *(const bf16x8*)(wf + s * 2048);          // coalesced 1KB
            bf16x8 bf1 = *(const bf16x8*)(wf + s * 2048 + 1024);   // coalesced 1KB
            const int co = (s * 64 + lq * 16) ^ swz;
            bf16x8 a0 = *(const bf16x8*)(ar0 + co);
            bf16x8 a1 = *(const bf16x8*)(ar1 + co);
            acc00 = __builtin_amdgcn_mfma_f32_16x16x32_bf16(a0, bf0, acc00, 0, 0, 0);
            acc01 = __builtin_amdgcn_mfma_f32_16x16x32_bf16(a0, bf1, acc01, 0, 0, 0);
            acc10 = __builtin_amdgcn_mfma_f32_16x16x32_bf16(a1, bf0, acc10, 0, 0, 0);
            acc11 = __builtin_amdgcn_mfma_f32_16x16x32_bf16(a1, bf1, acc11, 0, 0, 0);
        }
    }
    // tanh + w2-dot; reduce across the 16 h-lanes
    {
        const float b10 = b1[hb + l15], b11 = b1[hb + 16 + l15];
        const float w20 = w2[hb + l15], w21 = w2[hb + 16 + l15];
#pragma unroll
        for (int rf = 0; rf < 2; ++rf) {
            f32x4 aA = rf ? acc10 : acc00;
            f32x4 aB = rf ? acc11 : acc01;
#pragma unroll
            for (int r = 0; r < 4; ++r) {
                float p0 = fminf(fmaxf(aA[r] + b10, -10.f), 10.f);
                float p1 = fminf(fmaxf(aB[r] + b11, -10.f), 10.f);
                float e0 = __expf(2.f * p0), e1 = __expf(2.f * p1);
                float v = (e0 - 1.f) / (e0 + 1.f) * w20 + (e1 - 1.f) / (e1 + 1.f) * w21;
                v += __shfl_xor(v, 1); v += __shfl_xor(v, 2);
                v += __shfl_xor(v, 4); v += __shfl_xor(v, 8);
                if (l15 == 0) sred[rf * 16 + lq * 4 + r][wid] = v;
            }
        }
    }
    __syncthreads();

    // ---- chunk softmax (threads 0..31) ----
    if (t < 32) {
        float4 s4 = *(const float4*)&sred[t][0];
        float ssum = s4.x + s4.y + s4.z + s4.w + b2[0];
        int valid = m8[row0 + t];
        float score = valid ? ssum : -INFINITY;
        float mx = score;
        mx = fmaxf(mx, __shfl_xor(mx, 1));  mx = fmaxf(mx, __shfl_xor(mx, 2));
        mx = fmaxf(mx, __shfl_xor(mx, 4));  mx = fmaxf(mx, __shfl_xor(mx, 8));
        mx = fmaxf(mx, __shfl_xor(mx, 16));
        float e = valid ? __expf(score - mx) : 0.f;
        wrow[t] = e;
        float ts = e, tc = valid ? 1.f : 0.f;
        ts += __shfl_xor(ts, 1);  tc += __shfl_xor(tc, 1);
        ts += __shfl_xor(ts, 2);  tc += __shfl_xor(tc, 2);
        ts += __shfl_xor(ts, 4);  tc += __shfl_xor(tc, 4);
        ts += __shfl_xor(ts, 8);  tc += __shfl_xor(tc, 8);
        ts += __shfl_xor(ts, 16); tc += __shfl_xor(tc, 16);
        if (t == 0) { mc[blk] = mx; sc[blk] = ts; cnt[blk] = tc; }
    }
    __syncthreads();

    // ---- attn replay: thread owns bf16 cols (2t, 2t+1) ----
    float a0 = 0.f, a1 = 0.f;
#pragma unroll 8
    for (int r = 0; r < 32; ++r) {
        float w = wrow[r];
        unsigned u = *(const unsigned*)(At + r * 1024 + ((t * 4) ^ ((r & 7) << 4)));
        a0 = fmaf(w, bflo(u), a0);
        a1 = fmaf(w, bfhi(u), a1);
    }

    // ---- combine half-partials (sum, then max) via cpool ----
    *(float4*)&cpool[H][c4 * 4] = make_float4(ps[0], ps[1], ps[2], ps[3]);
    __syncthreads();
    float sv0 = cpool[0][2 * t] + cpool[1][2 * t];
    float sv1 = cpool[0][2 * t + 1] + cpool[1][2 * t + 1];
    __syncthreads();
    *(float4*)&cpool[H][c4 * 4] = make_float4(pm[0], pm[1], pm[2], pm[3]);
    __syncthreads();
    float mv0 = fmaxf(cpool[0][2 * t], cpool[1][2 * t]);
    float mv1 = fmaxf(cpool[0][2 * t + 1], cpool[1][2 * t + 1]);

    const size_t ob = (size_t)blk * DD + 2 * t;
    *(float2*)(attnp + ob) = make_float2(a0, a1);
    *(float2*)(sump + ob)  = make_float2(sv0, sv1);
    *(float2*)(maxp + ob)  = make_float2(mv0, mv1);
}

// ---- tail helpers (512-thread block reductions) ----------------------------
__device__ __forceinline__ float gmsp_bsum(float v, float* red, int t) {
    __syncthreads();
    red[t] = v; __syncthreads();
    for (int s = 256; s > 0; s >>= 1) { if (t < s) red[t] += red[t + s]; __syncthreads(); }
    return red[0];
}
__device__ __forceinline__ float gmsp_bmax(float v, float* red, int t) {
    __syncthreads();
    red[t] = v; __syncthreads();
    for (int s = 256; s > 0; s >>= 1) { if (t < s) red[t] = fmaxf(red[t], red[t + s]); __syncthreads(); }
    return red[0];
}

// ---- tail: 512 threads, one column/thread, k-split x4 MLP loops ------------
__global__ __launch_bounds__(512) void gmsp_tail(
    const float* __restrict__ attnp, const float* __restrict__ sump,
    const float* __restrict__ maxp, const float* __restrict__ mc,
    const float* __restrict__ sc, const float* __restrict__ cnt,
    const float* __restrict__ gate_w1, const float* __restrict__ gate_b1,
    const float* __restrict__ gln_g, const float* __restrict__ gln_b,
    const float* __restrict__ gate_w2, const float* __restrict__ gate_b2,
    const float* __restrict__ out_w, const float* __restrict__ out_b,
    const float* __restrict__ oln_g, const float* __restrict__ oln_b,
    float* __restrict__ out)
{
    __shared__ float comb[3 * DD];
    __shared__ float wvec[DD];
    __shared__ float red[512];
    __shared__ float ef[NCH];
    __shared__ float part[4][DD];
    int b = blockIdx.x, t = threadIdx.x;   // 512 threads; col = t

    // flash stats over 128 chunks
    float mcv = (t < NCH) ? mc[b * NCH + t] : -INFINITY;
    float M = gmsp_bmax(mcv, red, t);
    float e = (t < NCH && mcv != -INFINITY) ? __expf(mcv - M) : 0.f;
    if (t < NCH) ef[t] = e;
    float T = gmsp_bsum(e * ((t < NCH) ? sc[b * NCH + t] : 0.f), red, t);
    float C = gmsp_bsum((t < NCH) ? cnt[b * NCH + t] : 0.f, red, t);
    float invT = T > 0.f ? 1.f / T : 0.f;
    C = fmaxf(C, MEPS);
    __syncthreads();

    // per-column combine (col = t)
    float ax = 0.f, sx = 0.f, mx = -INFINITY;
    for (int c = 0; c < NCH; ++c) {
        size_t base = (size_t)(b * NCH + c) * DD + t;
        ax = fmaf(ef[c], attnp[base], ax);
        sx += sump[base];
        mx = fmaxf(mx, maxp[base]);
    }
    ax *= invT;
    float meanx = sx / C;
    if (isinf(mx)) mx = 0.f;

    comb[t] = ax;
    comb[DD + t] = mx;
    comb[2 * DD + t] = meanx;
    __syncthreads();

    // gate linear1: k-split x4, float4 columns (384 iters)
    const int th = t & 127, kh = t >> 7;
    {
        float4 g4 = make_float4(0.f, 0.f, 0.f, 0.f);
        const float* gw = gate_w1 + (size_t)kh * 384 * DD + th * 4;
        for (int k = 0; k < 384; ++k) {
            float cv = comb[kh * 384 + k];
            float4 wv = *(const float4*)(gw + (size_t)k * DD);
            g4.x = fmaf(cv, wv.x, g4.x); g4.y = fmaf(cv, wv.y, g4.y);
            g4.z = fmaf(cv, wv.z, g4.z); g4.w = fmaf(cv, wv.w, g4.w);
        }
        *(float4*)&part[kh][th * 4] = g4;
    }
    __syncthreads();
    float gx = part[0][t] + part[1][t] + part[2][t] + part[3][t] + gate_b1[t];

    float mg = gmsp_bsum(gx, red, t) * (1.f / DD);
    float vg = gmsp_bsum(gx * gx, red, t) * (1.f / DD) - mg * mg;
    float inv = rsqrtf(vg + LN_EPS);
    gx = (gx - mg) * inv * gln_g[t] + gln_b[t];
    gx = 0.5f * gx * (1.f + erff(gx * 0.70710678118654752f));

    float l0 = gmsp_bsum(gx * gate_w2[t * 3 + 0], red, t) + gate_b2[0];
    float l1 = gmsp_bsum(gx * gate_w2[t * 3 + 1], red, t) + gate_b2[1];
    float l2 = gmsp_bsum(gx * gate_w2[t * 3 + 2], red, t) + gate_b2[2];
    float mxl = fmaxf(l0, fmaxf(l1, l2));
    float e0 = __expf(l0 - mxl), e1 = __expf(l1 - mxl), e2 = __expf(l2 - mxl);
    float ie = 1.f / (e0 + e1 + e2);
    float gw0 = e0 * ie, gw1 = e1 * ie, gw2 = e2 * ie;

    wvec[t] = ax * gw0 + mx * gw1 + meanx * gw2;
    __syncthreads();

    // out projection: k-split x4, float4 columns (128 iters)
    {
        float4 o4 = make_float4(0.f, 0.f, 0.f, 0.f);
        const float* ow = out_w + (size_t)kh * 128 * DD + th * 4;
        for (int k = 0; k < 128; ++k) {
            float wvk = wvec[kh * 128 + k];
            float4 w4 = *(const float4*)(ow + (size_t)k * DD);
            o4.x = fmaf(wvk, w4.x, o4.x); o4.y = fmaf(wvk, w4.y, o4.y);
            o4.z = fmaf(wvk, w4.z, o4.z); o4.w = fmaf(wvk, w4.w, o4.w);
        }
        *(float4*)&part[kh][th * 4] = o4;
    }
    __syncthreads();
    float ox = part[0][t] + part[1][t] + part[2][t] + part[3][t] + out_b[t];

    float mo = gmsp_bsum(ox, red, t) * (1.f / DD);
    float vo = gmsp_bsum(ox * ox, red, t) * (1.f / DD) - mo * mo;
    float io = rsqrtf(vo + LN_EPS);
    out[(size_t)b * DD + t] = (ox - mo) * io * oln_g[t] + oln_b[t];
}

extern "C" void kernel_launch(void* const* d_in, const int* in_sizes, int n_in,
                              void* d_out, int out_size, void* d_ws, size_t ws_size,
                              hipStream_t stream) {
    const float* x        = (const float*)d_in[0];
    const void*  mask     = d_in[1];
    const float* attn_w1  = (const float*)d_in[2];
    const float* attn_b1  = (const float*)d_in[3];
    const float* attn_w2  = (const float*)d_in[4];
    const float* attn_b2  = (const float*)d_in[5];
    const float* gate_w1  = (const float*)d_in[6];
    const float* gate_b1  = (const float*)d_in[7];
    const float* gln_g    = (const float*)d_in[8];
    const float* gln_b    = (const float*)d_in[9];
    const float* gate_w2  = (const float*)d_in[10];
    const float* gate_b2  = (const float*)d_in[11];
    const float* out_w    = (const float*)d_in[12];
    const float* out_b    = (const float*)d_in[13];
    const float* oln_g    = (const float*)d_in[14];
    const float* oln_b    = (const float*)d_in[15];
    float* out = (float*)d_out;

    char* p = (char*)d_ws;
    unsigned char* m8 = (unsigned char*)p;      p += (size_t)BB * NN;             // 128 KB
    unsigned short* w1f = (unsigned short*)p;   p += (size_t)DD * HH * 2;         // 128 KB
    float* attnp = (float*)p;                   p += (size_t)BB * NCH * DD * 4;   // 8 MB
    float* sump = (float*)p;                    p += (size_t)BB * NCH * DD * 4;   // 8 MB
    float* maxp = (float*)p;                    p += (size_t)BB * NCH * DD * 4;   // 8 MB
    float* mc = (float*)p;                      p += (size_t)BB * NCH * 4;
    float* sc = (float*)p;                      p += (size_t)BB * NCH * 4;
    float* cnt = (float*)p;                     p += (size_t)BB * NCH * 4;

    gmsp_prep<<<768, 256, 0, stream>>>(mask, m8, attn_w1, w1f);
    gmsp_fused<<<BB * NCH, 256, 0, stream>>>(x, w1f, attn_b1, attn_w2, attn_b2, m8,
                                             attnp, sump, maxp, mc, sc, cnt);
    gmsp_tail<<<BB, 512, 0, stream>>>(attnp, sump, maxp, mc, sc, cnt,
                                      gate_w1, gate_b1, gln_g, gln_b, gate_w2, gate_b2,
                                      out_w, out_b, oln_g, oln_b, out);
}